// Round 1
// baseline (2721.861 us; speedup 1.0000x reference)
//
#include <hip/hip_runtime.h>
#include <hip/hip_bf16.h>
#include <stdint.h>

#define DIMV 64
#define HV 1024
#define BATCHV 32768
#define TB 16
#define NTHR 256
#define XSTRIDE 68     // floats; 68%32=4 -> bank-spread, 272B row = 16B aligned
#define HSTRIDE 1048   // bf16 elems; 2096B row = 16B aligned; dword stride 524 -> 2-way max
#define ACCSTRIDE 132  // floats

// Sorted-by-degree layout: degree d = h % 63. Groups d=0..15 have 17 units, 16..62 have 16.
// cumstart(d) = number of hidden units with degree < d.
__device__ __forceinline__ int cumstart_d(int d) { return 16 * d + (d < 16 ? d : 16); }
__device__ __forceinline__ int orig_of(int s) {
    int d, k;
    if (s < 272) { d = s / 17; k = s - 17 * d; }
    else { int s2 = s - 272; d = 16 + (s2 >> 4); k = s2 & 15; }
    return d + 63 * k;
}

__device__ __forceinline__ ushort f2bf(float v) {
    __hip_bfloat16 b = __float2bfloat16(v);
    return *reinterpret_cast<ushort*>(&b);
}
__device__ __forceinline__ float bf2f(ushort s) {
    return __uint_as_float(((uint32_t)s) << 16);
}

// Pre-sort weights by hidden-unit degree; transpose for contiguous per-unit rows.
// W1T[s][i]   = W1[i][orig(s)]            [1024][64]
// W2T[s2][s1] = W2[orig(s1)][orig(s2)]    [1024][1024]
// W3s[s2][c]  = W3[orig(s2)][c]           [1024][128]
__global__ void prep_all(const float* __restrict__ W1, const float* __restrict__ W2,
                         const float* __restrict__ W3, const float* __restrict__ b1,
                         const float* __restrict__ b2,
                         float* __restrict__ W1T, float* __restrict__ W2T,
                         float* __restrict__ W3s, float* __restrict__ b1s,
                         float* __restrict__ b2s)
{
    int idx = blockIdx.x * blockDim.x + threadIdx.x;
    if (idx < HV * HV) {
        int s2 = idx >> 10, s1 = idx & (HV - 1);
        W2T[(size_t)s2 * HV + s1] = W2[(size_t)orig_of(s1) * HV + orig_of(s2)];
    }
    if (idx < HV * DIMV) {
        int s = idx >> 6, i = idx & 63;
        W1T[(size_t)s * DIMV + i] = W1[(size_t)i * HV + orig_of(s)];
    }
    if (idx < HV * 2 * DIMV) {
        int s = idx >> 7, c = idx & 127;
        W3s[(size_t)s * 128 + c] = W3[(size_t)orig_of(s) * 128 + c];
    }
    if (idx < HV) {
        int o = orig_of(idx);
        b1s[idx] = b1[o];
        b2s[idx] = b2[o];
    }
}

__global__ __launch_bounds__(NTHR, 2)
void maf_main(const float* __restrict__ Uin, const float* __restrict__ b3,
              const float* __restrict__ W1T, const float* __restrict__ W2T,
              const float* __restrict__ W3s, const float* __restrict__ b1s,
              const float* __restrict__ b2s, float* __restrict__ out)
{
    extern __shared__ char smem[];
    ushort* h1  = (ushort*)smem;                        // [TB][HSTRIDE] bf16 bits, zero-init
    ushort* h2  = h1 + TB * HSTRIDE;                    // [TB][HSTRIDE]
    float*  xs  = (float*)(h2 + TB * HSTRIDE);          // [TB][XSTRIDE]
    float*  acc = xs + TB * XSTRIDE;                    // [TB][ACCSTRIDE]
    float*  logd = acc + TB * ACCSTRIDE;                // [TB]

    const int tid = threadIdx.x;
    const int r   = tid & (TB - 1);   // batch row within tile
    const int uu  = tid >> 4;         // unit/col slot 0..15
    const int row0 = blockIdx.x * TB;

    // Zero-init: padded tails of h1/x read-before-write must contribute 0.
    for (int i = tid; i < TB * HSTRIDE; i += NTHR) { h1[i] = 0; h2[i] = 0; }
    for (int i = tid; i < TB * XSTRIDE; i += NTHR) xs[i] = 0.f;
    for (int i = tid; i < TB * ACCSTRIDE; i += NTHR) acc[i] = 0.f;
    if (tid < TB) logd[tid] = 0.f;
    __syncthreads();

    for (int t = 0; t < DIMV; ++t) {
        if (t > 0) {
            const int d    = t - 1;
            const int goff = cumstart_d(d);
            const int gsz  = (d < 16) ? 17 : 16;

            // ---- phase a: finalize h1 group deg d: relu(b1 + x[0..t-1] . W1col) ----
            {
                const int nIt = (t + 3) >> 2;           // x beyond t is zero
                const float4* xrow = (const float4*)(xs + r * XSTRIDE);
                for (int j = uu; j < gsz; j += 16) {
                    const float4* wrow = (const float4*)(W1T + (size_t)(goff + j) * DIMV);
                    float a0 = b1s[goff + j], a1 = 0.f;
                    for (int it = 0; it < nIt; ++it) {
                        float4 w = wrow[it], xv = xrow[it];
                        a0 += w.x * xv.x + w.y * xv.y;
                        a1 += w.z * xv.z + w.w * xv.w;
                    }
                    h1[r * HSTRIDE + goff + j] = f2bf(fmaxf(a0 + a1, 0.f));
                }
            }
            __syncthreads();

            // ---- phase b (dominant): finalize h2 group deg d: relu(b2 + h1[0..K) . W2col) ----
            {
                const int K   = cumstart_d(t);          // #h1 units with deg <= d
                const int nIt = (K + 7) >> 3;           // h1 beyond K is zero
                const uint4* hrow = (const uint4*)(h1 + (size_t)r * HSTRIDE);
                for (int j = uu; j < gsz; j += 16) {
                    const float4* wrow = (const float4*)(W2T + (size_t)(goff + j) * HV);
                    float a0 = b2s[goff + j], a1 = 0.f;
                    #pragma unroll 2
                    for (int it = 0; it < nIt; ++it) {
                        uint4 hh = hrow[it];
                        float4 w0 = wrow[2 * it], w1 = wrow[2 * it + 1];
                        a0 += w0.x * __uint_as_float(hh.x << 16);
                        a1 += w0.y * __uint_as_float(hh.x & 0xffff0000u);
                        a0 += w0.z * __uint_as_float(hh.y << 16);
                        a1 += w0.w * __uint_as_float(hh.y & 0xffff0000u);
                        a0 += w1.x * __uint_as_float(hh.z << 16);
                        a1 += w1.y * __uint_as_float(hh.z & 0xffff0000u);
                        a0 += w1.z * __uint_as_float(hh.w << 16);
                        a1 += w1.w * __uint_as_float(hh.w & 0xffff0000u);
                    }
                    h2[r * HSTRIDE + goff + j] = f2bf(fmaxf(a0 + a1, 0.f));
                }
            }
            __syncthreads();

            // ---- phase c: acc[r][0..127] += h2grp . W3s rows (cols with deg<=d are dead, safe) ----
            {
                float s0 = 0, s1 = 0, s2 = 0, s3 = 0, s4 = 0, s5 = 0, s6 = 0, s7 = 0;
                for (int j = 0; j < gsz; ++j) {
                    float hv = bf2f(h2[r * HSTRIDE + goff + j]);
                    const float4* w3r = (const float4*)(W3s + (size_t)(goff + j) * 128 + uu * 8);
                    float4 wa = w3r[0], wb = w3r[1];
                    s0 += hv * wa.x; s1 += hv * wa.y; s2 += hv * wa.z; s3 += hv * wa.w;
                    s4 += hv * wb.x; s5 += hv * wb.y; s6 += hv * wb.z; s7 += hv * wb.w;
                }
                float4* arv = (float4*)(acc + r * ACCSTRIDE + uu * 8);
                float4 A0 = arv[0], A1 = arv[1];
                A0.x += s0; A0.y += s1; A0.z += s2; A0.w += s3;
                A1.x += s4; A1.y += s5; A1.z += s6; A1.w += s7;
                arv[0] = A0; arv[1] = A1;
            }
            __syncthreads();
        }

        // ---- phase d: x[t] = u[t]*exp(ls_t) + mu_t ; logd += ls_t ----
        if (tid < TB) {
            float mu = b3[t] + acc[tid * ACCSTRIDE + t];
            float ls = b3[DIMV + t] + acc[tid * ACCSTRIDE + DIMV + t];
            float uv = Uin[(size_t)(row0 + tid) * DIMV + t];
            xs[tid * XSTRIDE + t] = uv * expf(ls) + mu;
            logd[tid] += ls;
        }
        __syncthreads();
    }

    // ---- write outputs: x [B][64] then logd [B] ----
    {
        int rr = tid >> 4, c4 = tid & 15;
        float4 v = *(const float4*)(xs + rr * XSTRIDE + c4 * 4);
        ((float4*)out)[((size_t)(row0 + rr)) * 16 + c4] = v;
    }
    if (tid < TB) out[(size_t)BATCHV * DIMV + row0 + tid] = logd[tid];
}

extern "C" void kernel_launch(void* const* d_in, const int* in_sizes, int n_in,
                              void* d_out, int out_size, void* d_ws, size_t ws_size,
                              hipStream_t stream) {
    const float* U  = (const float*)d_in[0];
    const float* W1 = (const float*)d_in[1];
    const float* b1 = (const float*)d_in[2];
    const float* W2 = (const float*)d_in[3];
    const float* b2 = (const float*)d_in[4];
    const float* W3 = (const float*)d_in[5];
    const float* b3 = (const float*)d_in[6];
    float* out = (float*)d_out;

    char* ws = (char*)d_ws;
    float* W2T = (float*)ws;                               // 4 MB
    float* W1T = (float*)(ws + (size_t)HV * HV * 4);       // 256 KB
    float* W3s = W1T + (size_t)HV * DIMV;                  // 512 KB
    float* b1s = W3s + (size_t)HV * 2 * DIMV;              // 4 KB
    float* b2s = b1s + HV;                                 // 4 KB

    prep_all<<<(HV * HV + 255) / 256, 256, 0, stream>>>(W1, W2, W3, b1, b2,
                                                        W1T, W2T, W3s, b1s, b2s);

    const int smem_bytes = TB * HSTRIDE * 2 * 2 + TB * XSTRIDE * 4 + TB * ACCSTRIDE * 4 + TB * 4;
    hipFuncSetAttribute(reinterpret_cast<const void*>(&maf_main),
                        hipFuncAttributeMaxDynamicSharedMemorySize, smem_bytes);
    maf_main<<<BATCHV / TB, NTHR, smem_bytes, stream>>>(U, b3, W1T, W2T, W3s, b1s, b2s, out);
}

// Round 2
// 664.544 us; speedup vs baseline: 4.0958x; 4.0958x over previous
//
#include <hip/hip_runtime.h>
#include <hip/hip_bf16.h>
#include <stdint.h>

#define TB 16
#define HS1 1032      // h1 row stride (bf16): 2064B = 129 quads, odd -> bank-spread, 16B-aligned
#define XST 68        // xs row stride (f32): 272B, 16B-aligned
#define NWG 2048

typedef __attribute__((ext_vector_type(8))) short bf16x8;
typedef __attribute__((ext_vector_type(4))) float f32x4;

// degree d = h % 63; groups d=0..15 have 17 units, 16..62 have 16.
__device__ __forceinline__ int cumstart_d(int d) { return 16 * d + (d < 16 ? d : 16); }
__device__ __forceinline__ int orig_of(int s) {
    int d, k;
    if (s < 272) { d = s / 17; k = s - 17 * d; }
    else { int s2 = s - 272; d = 16 + (s2 >> 4); k = s2 & 15; }
    return d + 63 * k;
}
__device__ __forceinline__ ushort f2bf(float v) {
    __hip_bfloat16 b = __float2bfloat16(v);
    return *reinterpret_cast<ushort*>(&b);
}

// W1T [1024][64] f32 ; W2Tb [1040][1024] bf16 (unit-major, k contiguous, sorted both dims)
// W3b [128][2016] bf16 (col-major; k = d*32+j zero-padded per 32-wide group) ; b1s,b2s [1024] f32
__global__ void prep_all(const float* __restrict__ W1, const float* __restrict__ W2,
                         const float* __restrict__ W3, const float* __restrict__ b1,
                         const float* __restrict__ b2, float* __restrict__ W1T,
                         ushort* __restrict__ W2Tb, ushort* __restrict__ W3b,
                         float* __restrict__ b1s, float* __restrict__ b2s)
{
    int idx = blockIdx.x * blockDim.x + threadIdx.x;
    if (idx < 1040 * 1024) {
        int s2 = idx >> 10, s1 = idx & 1023;
        float v = (s2 < 1024) ? W2[(size_t)orig_of(s1) * 1024 + orig_of(s2)] : 0.f;
        W2Tb[idx] = f2bf(v);
    }
    if (idx < 128 * 2016) {
        int c = idx / 2016, kk = idx - c * 2016;
        int d = kk >> 5, j = kk & 31;
        int g = (d < 16) ? 17 : 16;
        float v = (j < g) ? W3[(size_t)orig_of(cumstart_d(d) + j) * 128 + c] : 0.f;
        W3b[idx] = f2bf(v);
    }
    if (idx < 1024 * 64) {
        int s = idx >> 6, i = idx & 63;
        W1T[idx] = W1[(size_t)i * 1024 + orig_of(s)];
    }
    if (idx < 1024) { int o = orig_of(idx); b1s[idx] = b1[o]; b2s[idx] = b2[o]; }
}

__global__ __launch_bounds__(256, 3)
void maf_main(const float* __restrict__ U, const float* __restrict__ b3,
              const float* __restrict__ W1T, const ushort* __restrict__ W2Tb,
              const ushort* __restrict__ W3b, const float* __restrict__ b1s,
              const float* __restrict__ b2s, float* __restrict__ out)
{
    __shared__ __align__(16) ushort h1[TB * HS1];      // 33.0 KB  h1 history (bf16, zero-init)
    __shared__ __align__(16) float  pc[8 * 16 * 20];   // 10.2 KB  partial C [kw*2+ti][col][row(20)]
    __shared__ __align__(16) ushort h2t[16 * 40];      // 1.3 KB   current h2 group [row][j(40)]
    __shared__ __align__(16) float  xs[TB * XST];      // 4.4 KB   x (fp32, zero-init)
    __shared__ __align__(16) float  mucol[16];
    __shared__ __align__(16) float  lscol[16];
    __shared__ __align__(16) float  logd[16];

    const int tid = threadIdx.x;
    const int lane = tid & 63;
    const int wv = tid >> 6;        // wave 0..3
    const int r16 = lane & 15;
    const int q = lane >> 4;
    const int row0 = blockIdx.x * TB;

    for (int i = tid; i < TB * HS1; i += 256) h1[i] = 0;
    for (int i = tid; i < TB * XST; i += 256) xs[i] = 0.f;
    if (tid < 16) logd[tid] = 0.f;
    __syncthreads();

    // persistent output accumulator: wave wv owns cols [wv*32, wv*32+32): two 16x16 C tiles
    f32x4 acc0 = {0.f, 0.f, 0.f, 0.f};
    f32x4 acc1 = {0.f, 0.f, 0.f, 0.f};

    for (int t = 0; t < 64; ++t) {
        float uvpre = (tid < 16) ? U[(size_t)(row0 + tid) * 64 + t] : 0.f;  // prefetch
        if (t > 0) {
            const int d = t - 1;
            const int goff = 16 * d + (d < 16 ? d : 16);
            const int gsz = (d < 16) ? 17 : 16;

            // ---- phase a (VALU, fp32): finalize h1 group deg d ----
            {
                const int nIt = (t + 3) >> 2;
                for (int task = tid; task < gsz * 16; task += 256) {
                    const int j = task >> 4, r = task & 15;
                    const float4* wr = (const float4*)(W1T + ((size_t)(goff + j) << 6));
                    const float4* xr = (const float4*)(xs + r * XST);
                    float a0 = b1s[goff + j], a1 = 0.f;
                    for (int it = 0; it < nIt; ++it) {
                        float4 w = wr[it], xv = xr[it];
                        a0 += w.x * xv.x + w.y * xv.y;
                        a1 += w.z * xv.z + w.w * xv.w;
                    }
                    h1[r * HS1 + goff + j] = f2bf(fmaxf(a0 + a1, 0.f));
                }
            }
            __syncthreads();

            // ---- phase b (MFMA): h2 group = h1[16r][0..K) x W2Tb, K-split over 4 waves ----
            {
                const int K = 16 * t + (t < 16 ? t : 16);
                const int NC = (K + 31) >> 5;       // zero h1 tail makes the pad free
                f32x4 c0 = {0.f, 0.f, 0.f, 0.f};
                f32x4 c1 = {0.f, 0.f, 0.f, 0.f};
                const ushort* arow = h1 + r16 * HS1 + q * 8;
                const ushort* brow0 = W2Tb + ((size_t)(goff + r16) << 10) + q * 8;
                const ushort* brow1 = brow0 + (16 << 10);
                if (gsz > 16) {
                    for (int kc = wv; kc < NC; kc += 4) {
                        bf16x8 af = *(const bf16x8*)(arow + kc * 32);
                        bf16x8 b0 = *(const bf16x8*)(brow0 + kc * 32);
                        bf16x8 b1f = *(const bf16x8*)(brow1 + kc * 32);
                        c0 = __builtin_amdgcn_mfma_f32_16x16x32_bf16(af, b0, c0, 0, 0, 0);
                        c1 = __builtin_amdgcn_mfma_f32_16x16x32_bf16(af, b1f, c1, 0, 0, 0);
                    }
                } else {
                    for (int kc = wv; kc < NC; kc += 4) {
                        bf16x8 af = *(const bf16x8*)(arow + kc * 32);
                        bf16x8 b0 = *(const bf16x8*)(brow0 + kc * 32);
                        c0 = __builtin_amdgcn_mfma_f32_16x16x32_bf16(af, b0, c0, 0, 0, 0);
                    }
                }
                *(f32x4*)(pc + ((wv * 2 + 0) * 16 + r16) * 20 + q * 4) = c0;
                if (gsz > 16)
                    *(f32x4*)(pc + ((wv * 2 + 1) * 16 + r16) * 20 + q * 4) = c1;
            }
            __syncthreads();

            // ---- cross-wave reduce -> h2t (bf16, zero-padded to 32) ----
            {
                const int r = tid & 15, c = tid >> 4;
                float s0 = b2s[goff + c]
                         + pc[(0 * 16 + c) * 20 + r] + pc[(2 * 16 + c) * 20 + r]
                         + pc[(4 * 16 + c) * 20 + r] + pc[(6 * 16 + c) * 20 + r];
                h2t[r * 40 + c] = f2bf(fmaxf(s0, 0.f));
                ushort v1 = 0;
                if (gsz > 16 && c == 0) {
                    float s1 = b2s[goff + 16]
                             + pc[(1 * 16) * 20 + r] + pc[(3 * 16) * 20 + r]
                             + pc[(5 * 16) * 20 + r] + pc[(7 * 16) * 20 + r];
                    v1 = f2bf(fmaxf(s1, 0.f));
                }
                h2t[r * 40 + 16 + c] = (c == 0) ? v1 : (ushort)0;
            }
            __syncthreads();

            // ---- phase c (MFMA): acc[16r][128c] += h2grp x W3grp, cols split over waves ----
            {
                bf16x8 af = *(const bf16x8*)(h2t + r16 * 40 + q * 8);
                const ushort* b3r = W3b + (size_t)(wv * 32 + r16) * 2016 + d * 32 + q * 8;
                bf16x8 b0 = *(const bf16x8*)(b3r);
                bf16x8 b1f = *(const bf16x8*)(b3r + 16 * 2016);
                acc0 = __builtin_amdgcn_mfma_f32_16x16x32_bf16(af, b0, acc0, 0, 0, 0);
                acc1 = __builtin_amdgcn_mfma_f32_16x16x32_bf16(af, b1f, acc1, 0, 0, 0);
            }
        }

        // ---- phase d: publish col t (mu) and col 64+t (ls), form x_t ----
        {
            const int w0 = t >> 5;
            const int ti0 = (t >> 4) & 1;
            const int c = t & 15;
            if (wv == w0 && r16 == c) {
                f32x4 v = ti0 ? acc1 : acc0;
                *(f32x4*)(mucol + q * 4) = v;
            }
            if (wv == 2 + w0 && r16 == c) {
                f32x4 v = ti0 ? acc1 : acc0;
                *(f32x4*)(lscol + q * 4) = v;
            }
            __syncthreads();
            if (tid < 16) {
                float mu = mucol[tid] + b3[t];
                float ls = lscol[tid] + b3[64 + t];
                xs[tid * XST + t] = uvpre * expf(ls) + mu;
                logd[tid] += ls;
            }
            __syncthreads();
        }
    }

    // ---- outputs: x [B][64] then logd [B] ----
    {
        const int rr = tid >> 4, c4 = tid & 15;
        float4 v = *(const float4*)(xs + rr * XST + c4 * 4);
        ((float4*)out)[((size_t)(row0 + rr)) * 16 + c4] = v;
    }
    if (tid < 16) out[(size_t)32768 * 64 + row0 + tid] = logd[tid];
}

extern "C" void kernel_launch(void* const* d_in, const int* in_sizes, int n_in,
                              void* d_out, int out_size, void* d_ws, size_t ws_size,
                              hipStream_t stream) {
    const float* U  = (const float*)d_in[0];
    const float* W1 = (const float*)d_in[1];
    const float* b1 = (const float*)d_in[2];
    const float* W2 = (const float*)d_in[3];
    const float* b2 = (const float*)d_in[4];
    const float* W3 = (const float*)d_in[5];
    const float* b3 = (const float*)d_in[6];
    float* out = (float*)d_out;

    char* ws = (char*)d_ws;
    ushort* W2Tb = (ushort*)ws;                                   // 2,129,920 B
    ushort* W3b  = (ushort*)(ws + 2129920);                       //   516,096 B
    float*  W1T  = (float*)(ws + 2129920 + 516096);               //   262,144 B
    float*  b1s  = (float*)(ws + 2129920 + 516096 + 262144);      //     4,096 B
    float*  b2s  = b1s + 1024;                                    //     4,096 B

    const int prep_threads = 1040 * 1024;
    prep_all<<<(prep_threads + 255) / 256, 256, 0, stream>>>(W1, W2, W3, b1, b2,
                                                             W1T, W2Tb, W3b, b1s, b2s);
    maf_main<<<NWG, 256, 0, stream>>>(U, b3, W1T, W2Tb, W3b, b1s, b2s, out);
}

// Round 3
// 449.526 us; speedup vs baseline: 6.0550x; 1.4783x over previous
//
#include <hip/hip_runtime.h>
#include <hip/hip_bf16.h>
#include <stdint.h>

#define HS1 1032   // h1 row stride (bf16): 2064B = 129 quads -> stride-1-like bank pattern
#define XB  72     // xb row stride (bf16): 144B = 9 quads

typedef __attribute__((ext_vector_type(8))) short bf16x8;
typedef __attribute__((ext_vector_type(4))) float f32x4;

// degree d = h % 63; groups d=0..15 have 17 units, 16..62 have 16.
__device__ __forceinline__ int cumstart_d(int d){ return 16*d + (d<16 ? d : 16); }
__device__ __forceinline__ int orig_of(int s){
    int d,k;
    if (s<272){ d = s/17; k = s-17*d; } else { int s2=s-272; d=16+(s2>>4); k=s2&15; }
    return d + 63*k;
}
__device__ __forceinline__ ushort f2bf(float v){
    __hip_bfloat16 b = __float2bfloat16(v);
    return *reinterpret_cast<ushort*>(&b);
}

// W2Tb [1024 unit][1024 k] bf16 (both dims degree-sorted)
// W1b  [63 d][2 kc][2 nt][16 n][32 k] bf16 (B-frag tiles for phase a, zero-padded)
// W3c  [63 d][8 cb][16 n][32 k] bf16 (B-frag tiles for phase c, k zero-padded past gsz)
__global__ void prep_all(const float* __restrict__ W1, const float* __restrict__ W2,
                         const float* __restrict__ W3, const float* __restrict__ b1,
                         const float* __restrict__ b2,
                         ushort* __restrict__ W2Tb, ushort* __restrict__ W1b,
                         ushort* __restrict__ W3c, float* __restrict__ b1s,
                         float* __restrict__ b2s)
{
    int idx = blockIdx.x * 256 + threadIdx.x;
    if (idx < 1024*1024) {
        int s2 = idx >> 10, s1 = idx & 1023;
        W2Tb[idx] = f2bf(W2[(size_t)orig_of(s1)*1024 + orig_of(s2)]);
    }
    if (idx < 63*4*512) {
        int tile = idx >> 9, w = idx & 511;
        int n = w >> 5, k2 = w & 31;
        int d = tile >> 2, kc = (tile >> 1) & 1, nt = tile & 1;
        int goff = cumstart_d(d), gsz = (d<16) ? 17 : 16;
        int uo = nt*16 + n;
        float v = (uo < gsz) ? W1[(size_t)(kc*32 + k2)*1024 + orig_of(goff+uo)] : 0.f;
        W1b[idx] = f2bf(v);
    }
    if (idx < 63*8*512) {
        int tile = idx >> 9, w = idx & 511;
        int n = w >> 5, k = w & 31;
        int d = tile >> 3, cb = tile & 7;
        int goff = cumstart_d(d), gsz = (d<16) ? 17 : 16;
        float v = (k < gsz) ? W3[(size_t)orig_of(goff+k)*128 + cb*16 + n] : 0.f;
        W3c[idx] = f2bf(v);
    }
    if (idx < 1024) { int o = orig_of(idx); b1s[idx]=b1[o]; b2s[idx]=b2[o]; }
}

__global__ __launch_bounds__(256, 4)
void maf_main(const float* __restrict__ U, const float* __restrict__ b3,
              const ushort* __restrict__ W2Tb, const ushort* __restrict__ W1b,
              const ushort* __restrict__ W3c, const float* __restrict__ b1s,
              const float* __restrict__ b2s, float* __restrict__ out)
{
    __shared__ __align__(16) ushort h1[16*HS1];   // 33.0 KB  bf16 h1 history (zero-init)
    __shared__ __align__(16) ushort xb[16*XB];    //  2.3 KB  bf16 x mirror (zero-init)
    __shared__ __align__(16) float  pc[3*16*20];  //  3.8 KB  phase-b partials [slot][unit][row20]
    __shared__ __align__(16) ushort h2t[16*40];   //  1.3 KB  current h2 group [row][32k padded]
    __shared__ float logd[16];                    // total 40.5 KB -> 4 WG/CU

    const int tid = threadIdx.x;
    const int wv = tid >> 6;
    const int lane = tid & 63;
    const int r16 = lane & 15;
    const int q = lane >> 4;
    const int row0 = blockIdx.x * 16;

    for (int i = tid; i < 16*HS1/2; i += 256) ((uint32_t*)h1)[i] = 0u;
    for (int i = tid; i < 16*XB/2;  i += 256) ((uint32_t*)xb)[i] = 0u;
    for (int i = tid; i < 16*40/2;  i += 256) ((uint32_t*)h2t)[i] = 0u;
    if (tid < 16) logd[tid] = 0.f;
    __syncthreads();

    // wave wv holds output cols: acc0 = mu cols [16wv,16wv+16), acc1 = ls cols [64+16wv, +16)
    f32x4 acc0 = {0.f,0.f,0.f,0.f}, acc1 = {0.f,0.f,0.f,0.f};

    for (int t = 0; t < 64; ++t) {
        const int ow = t >> 4, oc = t & 15;
        const bool owner = (wv == ow) && (r16 == oc);
        float u0=0.f,u1=0.f,u2=0.f,u3=0.f;
        if (owner) {                               // prefetch u for the 4 rows this lane owns
            const float* up = U + (size_t)(row0 + q*4)*64 + t;
            u0 = up[0]; u1 = up[64]; u2 = up[128]; u3 = up[192];
        }
        const float b3mu = b3[t], b3ls = b3[64+t];

        if (t > 0) {
            const int d    = t - 1;
            const int goff = cumstart_d(d);
            const int gsz  = (d<16) ? 17 : 16;
            const int E    = goff >> 5;                 // early chunks [0,E) need no barrier
            const int NC   = (goff + gsz + 31) >> 5;    // NC-E <= 2

            // prefetch phase-c B frags (data-independent)
            const ushort* w3p = W3c + (size_t)((d*8 + wv)*512) + r16*32 + q*8;
            const bf16x8 bc0 = *(const bf16x8*)(w3p);
            const bf16x8 bc1 = *(const bf16x8*)(w3p + 4*512);

            f32x4 c0 = {0.f,0.f,0.f,0.f};
            bf16x8 blate = {0,0,0,0,0,0,0,0};
            bool haveLate = false;

            if (wv == 3) {
                // ---- phase a (MFMA): h1 group d = relu(b1 + xb[16r][64k] . W1grp) ----
                const ushort* xrow = xb + r16*XB;
                bf16x8 a0 = *(const bf16x8*)(xrow + q*8);
                bf16x8 a1 = *(const bf16x8*)(xrow + 32 + q*8);
                const ushort* w1p = W1b + (size_t)(d*4*512) + r16*32 + q*8;
                bf16x8 wb0 = *(const bf16x8*)(w1p);
                bf16x8 wb1 = *(const bf16x8*)(w1p + 2*512);
                f32x4 h = {0.f,0.f,0.f,0.f};
                h = __builtin_amdgcn_mfma_f32_16x16x32_bf16(a0, wb0, h, 0,0,0);
                h = __builtin_amdgcn_mfma_f32_16x16x32_bf16(a1, wb1, h, 0,0,0);
                const float bb = b1s[goff + r16];
                #pragma unroll
                for (int e=0;e<4;++e)
                    h1[(q*4+e)*HS1 + goff + r16] = f2bf(fmaxf(h[e]+bb, 0.f));
                if (d < 16) {                          // 17th unit via second N-tile, col 0
                    bf16x8 wb2 = *(const bf16x8*)(w1p + 512);
                    bf16x8 wb3 = *(const bf16x8*)(w1p + 3*512);
                    f32x4 g = {0.f,0.f,0.f,0.f};
                    g = __builtin_amdgcn_mfma_f32_16x16x32_bf16(a0, wb2, g, 0,0,0);
                    g = __builtin_amdgcn_mfma_f32_16x16x32_bf16(a1, wb3, g, 0,0,0);
                    if (r16 == 0) {
                        const float bb1 = b1s[goff + 16];
                        #pragma unroll
                        for (int e=0;e<4;++e)
                            h1[(q*4+e)*HS1 + goff + 16] = f2bf(fmaxf(g[e]+bb1, 0.f));
                    }
                }
            } else if (wv < 2) {
                // prefetch the late-chunk B frag this wave will consume post-barrier
                const int kcl = E + wv;
                if (kcl < NC) {
                    blate = *(const bf16x8*)(W2Tb + ((size_t)(goff + r16) << 10) + kcl*32 + q*8);
                    haveLate = true;
                }
                const int stp = (d < 16) ? 2 : 3;      // early c0 K-split over 2 or 3 waves
                for (int kc = wv; kc < E; kc += stp) {
                    bf16x8 af  = *(const bf16x8*)(h1 + r16*HS1 + kc*32 + q*8);
                    bf16x8 bf_ = *(const bf16x8*)(W2Tb + ((size_t)(goff + r16) << 10) + kc*32 + q*8);
                    c0 = __builtin_amdgcn_mfma_f32_16x16x32_bf16(af, bf_, c0, 0,0,0);
                }
            } else {
                if (d >= 16) {                          // wave 2 joins c0 early-split
                    for (int kc = 2; kc < E; kc += 3) {
                        bf16x8 af  = *(const bf16x8*)(h1 + r16*HS1 + kc*32 + q*8);
                        bf16x8 bf_ = *(const bf16x8*)(W2Tb + ((size_t)(goff + r16) << 10) + kc*32 + q*8);
                        c0 = __builtin_amdgcn_mfma_f32_16x16x32_bf16(af, bf_, c0, 0,0,0);
                    }
                } else {                                // wave 2 computes c1 (17th unit) early
                    for (int kc = 0; kc < E; ++kc) {
                        bf16x8 af  = *(const bf16x8*)(h1 + r16*HS1 + kc*32 + q*8);
                        bf16x8 bf_ = *(const bf16x8*)(W2Tb + ((size_t)(goff + 16 + r16) << 10) + kc*32 + q*8);
                        c0 = __builtin_amdgcn_mfma_f32_16x16x32_bf16(af, bf_, c0, 0,0,0);
                    }
                }
            }
            __syncthreads();   // B1: h1 group d visible

            // ---- late chunks (contain group d) ----
            if (wv < 2) {
                if (haveLate) {
                    const int kcl = E + wv;
                    bf16x8 af = *(const bf16x8*)(h1 + r16*HS1 + kcl*32 + q*8);
                    c0 = __builtin_amdgcn_mfma_f32_16x16x32_bf16(af, blate, c0, 0,0,0);
                }
            } else if (wv == 2 && d < 16) {
                for (int kc = E; kc < NC; ++kc) {
                    bf16x8 af  = *(const bf16x8*)(h1 + r16*HS1 + kc*32 + q*8);
                    bf16x8 bf_ = *(const bf16x8*)(W2Tb + ((size_t)(goff + 16 + r16) << 10) + kc*32 + q*8);
                    c0 = __builtin_amdgcn_mfma_f32_16x16x32_bf16(af, bf_, c0, 0,0,0);
                }
            }
            if (wv < 3)
                *(f32x4*)(pc + (wv*16 + r16)*20 + q*4) = c0;
            __syncthreads();   // B2

            // ---- cross-wave reduce -> h2t ----
            {
                const int rr = tid & 15, cc = tid >> 4;
                float s = b2s[goff + cc] + pc[(0*16+cc)*20+rr] + pc[(1*16+cc)*20+rr];
                if (d >= 16) s += pc[(2*16+cc)*20+rr];
                h2t[rr*40 + cc] = f2bf(fmaxf(s, 0.f));
                if (cc == 15) {
                    ushort v = 0;
                    if (d < 16) {
                        float s1 = b2s[goff+16] + pc[(2*16+0)*20+rr];
                        v = f2bf(fmaxf(s1, 0.f));
                    }
                    h2t[rr*40 + 16] = v;
                }
            }
            __syncthreads();   // B3

            // ---- phase c: acc += h2grp x W3grp (B prefetched) ----
            {
                bf16x8 af = *(const bf16x8*)(h2t + r16*40 + q*8);
                acc0 = __builtin_amdgcn_mfma_f32_16x16x32_bf16(af, bc0, acc0, 0,0,0);
                acc1 = __builtin_amdgcn_mfma_f32_16x16x32_bf16(af, bc1, acc1, 0,0,0);
            }
        }

        // ---- publish: owner wave holds both mu (acc0) and ls (acc1) for col t ----
        if (owner) {
            #pragma unroll
            for (int e=0;e<4;++e) {
                const int m = q*4 + e;
                float mu = acc0[e] + b3mu;
                float ls = acc1[e] + b3ls;
                float uv = (e==0)?u0:(e==1)?u1:(e==2)?u2:u3;
                float xv = uv * expf(ls) + mu;
                out[(size_t)(row0 + m)*64 + t] = xv;     // fp32 x streamed directly
                xb[m*XB + t] = f2bf(xv);
                logd[m] += ls;
            }
        }
        __syncthreads();       // B4 (loop top): xb[t] visible to phase a of t+1
    }

    if (tid < 16) out[(size_t)32768*64 + row0 + tid] = logd[tid];
}

extern "C" void kernel_launch(void* const* d_in, const int* in_sizes, int n_in,
                              void* d_out, int out_size, void* d_ws, size_t ws_size,
                              hipStream_t stream) {
    const float* U  = (const float*)d_in[0];
    const float* W1 = (const float*)d_in[1];
    const float* b1 = (const float*)d_in[2];
    const float* W2 = (const float*)d_in[3];
    const float* b2 = (const float*)d_in[4];
    const float* W3 = (const float*)d_in[5];
    const float* b3 = (const float*)d_in[6];
    float* out = (float*)d_out;

    char* ws = (char*)d_ws;
    ushort* W2Tb = (ushort*)ws;                      // 2,097,152 B
    ushort* W1b  = (ushort*)(ws + 2097152);          //   258,048 B
    ushort* W3c  = (ushort*)(ws + 2355200);          //   516,096 B
    float*  b1s  = (float*)(ws + 2871296);           //     4,096 B
    float*  b2s  = (float*)(ws + 2875392);           //     4,096 B

    prep_all<<<4096, 256, 0, stream>>>(W1, W2, W3, b1, b2, W2Tb, W1b, W3c, b1s, b2s);
    maf_main<<<2048, 256, 0, stream>>>(U, b3, W2Tb, W1b, W3c, b1s, b2s, out);
}

// Round 4
// 351.072 us; speedup vs baseline: 7.7530x; 1.2804x over previous
//
#include <hip/hip_runtime.h>
#include <hip/hip_bf16.h>
#include <stdint.h>

typedef __attribute__((ext_vector_type(8))) short bf16x8;
typedef __attribute__((ext_vector_type(4))) float f32x4;
typedef __attribute__((ext_vector_type(4))) unsigned int u32x4;

#define MFMA __builtin_amdgcn_mfma_f32_16x16x32_bf16

// chunks of 32 h1-units needed at step t: ceil(cumstart(t)/32), cumstart(t)=16t+min(t,16)
__device__ __forceinline__ int nc_of(int t) {
    return (t <= 16) ? ((17 * t + 31) >> 5) : ((t + 2) >> 1);
}
__device__ __forceinline__ int orig_of(int s) {
    int d, k;
    if (s < 272) { d = s / 17; k = s - 17 * d; }
    else { int s2 = s - 272; d = 16 + (s2 >> 4); k = s2 & 15; }
    return d + 63 * k;
}
__device__ __forceinline__ ushort f2bf(float v) {
    __hip_bfloat16 b = __float2bfloat16(v);
    return *reinterpret_cast<ushort*>(&b);
}

// Frag-layouts (all lane-linear: frag element = base + lane*8 + e, coalesced 1KB/frag):
// W2f: per-degree-d B-frags for units goff(d)..goff(d)+15, chunks kc<NC(d+1), densely packed
//      at chunk offset off(d)=sum_{t<=d} NC(t). col=lane&15 -> unit goff+col, k=kc*32+(lane>>4)*8+e.
// W2g: [16 d][9 kc][512] B-frags for units goff(d)+16.. (17th h1 unit path, d<16).
// W1f: [63 d][2 kc2][2 nt][512] phase-a B-frags (k=input dim, col=unit, zero-pad past gsz).
// W3f: [63 d][8 cb][512] phase-c B-frags (k=unit-in-group zero-padded, col=output col cb*16+n).
__global__ void prep_all(const float* __restrict__ W1, const float* __restrict__ W2,
                         const float* __restrict__ W3, const float* __restrict__ b1,
                         const float* __restrict__ b2,
                         ushort* __restrict__ W2f, ushort* __restrict__ W2g,
                         ushort* __restrict__ W1f, ushort* __restrict__ W3f,
                         float* __restrict__ b1s, float* __restrict__ b2s)
{
    int idx = blockIdx.x * 256 + threadIdx.x;
    if (idx < 63 * 32 * 512) {                       // W2f
        int d = idx >> 14, rem = idx & 16383;
        int kc = rem >> 9, r = rem & 511;
        if (kc < nc_of(d + 1)) {
            int off = 0;
            for (int tt = 1; tt <= d; ++tt) off += nc_of(tt);
            int lane = r >> 3, e = r & 7;
            int col = lane & 15, k = kc * 32 + (lane >> 4) * 8 + e;
            int goff = (d < 16) ? 17 * d : 16 * d + 16;
            W2f[(size_t)(off + kc) * 512 + r] =
                f2bf(W2[(size_t)orig_of(k) * 1024 + orig_of(goff + col)]);
        }
    }
    if (idx < 16 * 9 * 512) {                        // W2g
        int d = idx / 4608, rem = idx - d * 4608;
        int r = rem & 511, kc = rem >> 9;
        int lane = r >> 3, e = r & 7;
        int col = lane & 15, k = kc * 32 + (lane >> 4) * 8 + e;
        W2g[idx] = f2bf(W2[(size_t)orig_of(k) * 1024 + orig_of(17 * d + 16 + col)]);
    }
    if (idx < 63 * 2048) {                           // W1f
        int d = idx >> 11, rem = idx & 2047;
        int kc2 = rem >> 10, nt = (rem >> 9) & 1, r = rem & 511;
        int lane = r >> 3, e = r & 7;
        int col = lane & 15, k = kc2 * 32 + (lane >> 4) * 8 + e;
        int goff = (d < 16) ? 17 * d : 16 * d + 16;
        int gsz = (d < 16) ? 17 : 16;
        int uo = nt * 16 + col;
        float v = (uo < gsz) ? W1[(size_t)k * 1024 + orig_of(goff + uo)] : 0.f;
        W1f[idx] = f2bf(v);
    }
    if (idx < 63 * 8 * 512) {                        // W3f
        int d = idx >> 12, rem = idx & 4095;
        int cb = rem >> 9, r = rem & 511;
        int lane = r >> 3, e = r & 7;
        int n = lane & 15, k = (lane >> 4) * 8 + e;
        int goff = (d < 16) ? 17 * d : 16 * d + 16;
        int gsz = (d < 16) ? 17 : 16;
        float v = (k < gsz) ? W3[(size_t)orig_of(goff + k) * 128 + cb * 16 + n] : 0.f;
        W3f[idx] = f2bf(v);
    }
    if (idx < 1024) { int o = orig_of(idx); b1s[idx] = b1[o]; b2s[idx] = b2[o]; }
}

template<int NCH, bool T2>
__device__ __forceinline__ void phase_b(const ushort* __restrict__ w2p,
                                        const ushort* __restrict__ w2gp,
                                        const char* h1b, int r16, int q, int lane8,
                                        f32x4& o1, f32x4& o2)
{
    bf16x8 bb[NCH];
    #pragma unroll
    for (int kc = 0; kc < NCH; ++kc)
        bb[kc] = *(const bf16x8*)(w2p + kc * 512 + lane8);
    bf16x8 gg[T2 ? NCH : 1];
    if constexpr (T2) {
        #pragma unroll
        for (int kc = 0; kc < NCH; ++kc)
            gg[kc] = *(const bf16x8*)(w2gp + kc * 512 + lane8);
    }
    f32x4 ce = {0,0,0,0}, co = {0,0,0,0}, ge = {0,0,0,0}, go = {0,0,0,0};
    #pragma unroll
    for (int kc = 0; kc < NCH; ++kc) {
        int bo = (r16 * 2048 + kc * 64 + q * 16) ^ ((r16 & 7) << 4);
        bf16x8 af = *(const bf16x8*)(h1b + bo);
        if (kc & 1) co = MFMA(af, bb[kc], co, 0, 0, 0);
        else        ce = MFMA(af, bb[kc], ce, 0, 0, 0);
        if constexpr (T2) {
            if (kc & 1) go = MFMA(af, gg[kc], go, 0, 0, 0);
            else        ge = MFMA(af, gg[kc], ge, 0, 0, 0);
        }
    }
    o1 = ce + co;
    if constexpr (T2) o2 = ge + go;
}

// 4 waves/WG, each wave owns a private 16-row batch slice: NO __syncthreads anywhere.
__global__ __launch_bounds__(256, 1)
void maf_main(const float* __restrict__ U, const float* __restrict__ b3,
              const ushort* __restrict__ W2f, const ushort* __restrict__ W2g,
              const ushort* __restrict__ W1f, const ushort* __restrict__ W3f,
              const float* __restrict__ b1s, const float* __restrict__ b2s,
              float* __restrict__ out)
{
    extern __shared__ char smem[];
    const int tid = threadIdx.x;
    const int w = tid >> 6, lane = tid & 63;
    const int r16 = lane & 15, q = lane >> 4;
    const int lane8 = lane * 8;
    char*   h1b = smem + w * 32768;                       // [16 row][1024 unit] bf16, XOR-swizzled
    ushort* xbs = (ushort*)(smem + 131072 + w * 2304);    // [16 row][72] bf16 x-mirror
    ushort* h2s = (ushort*)(smem + 140288 + w * 1024);    // [16 row][32] bf16 h2 group staging
    float*  lgd = (float*)(smem + 144384 + w * 64);       // [16] logdet
    const int grow0 = blockIdx.x * 64 + w * 16;

    {
        u32x4 z = {0u,0u,0u,0u};
        for (int i = lane; i < 2048; i += 64) *(u32x4*)(h1b + i * 16) = z;
        for (int i = lane; i < 576; i += 64) ((uint32_t*)xbs)[i] = 0u;
        for (int i = lane; i < 256; i += 64) ((uint32_t*)h2s)[i] = 0u;
        if (lane < 16) lgd[lane] = 0.f;
    }

    // persistent output acc: am = mu cols (0..63), al = ls cols (64..127); tile n = cols n*16..
    f32x4 am0={0,0,0,0},am1={0,0,0,0},am2={0,0,0,0},am3={0,0,0,0};
    f32x4 al0={0,0,0,0},al1={0,0,0,0},al2={0,0,0,0},al3={0,0,0,0};

    size_t w2off = 0;

    for (int t = 0; t < 64; ++t) {
        const int tt = t >> 4, oc = t & 15;
        const float b3mu = b3[t], b3ls = b3[64 + t];
        float uu[4] = {0.f, 0.f, 0.f, 0.f};
        if (r16 == oc) {
            #pragma unroll
            for (int e = 0; e < 4; ++e)
                uu[e] = U[(size_t)(grow0 + q * 4 + e) * 64 + t];
        }

        if (t > 0) {
            const int d = t - 1;
            const int goff = (d < 16) ? 17 * d : 16 * d + 16;

            // ---- phase a (MFMA): finalize h1 group d ----
            {
                const ushort* w1p = W1f + (size_t)d * 2048 + lane8;
                bf16x8 wf00 = *(const bf16x8*)(w1p);
                bf16x8 wf10 = *(const bf16x8*)(w1p + 1024);
                bf16x8 xa0 = *(const bf16x8*)(xbs + r16 * 72 + q * 8);
                bf16x8 xa1 = *(const bf16x8*)(xbs + r16 * 72 + 32 + q * 8);
                f32x4 h = {0,0,0,0};
                h = MFMA(xa0, wf00, h, 0, 0, 0);
                h = MFMA(xa1, wf10, h, 0, 0, 0);
                float bb1 = b1s[goff + r16];
                #pragma unroll
                for (int e = 0; e < 4; ++e) {
                    int row = q * 4 + e;
                    ushort hv = f2bf(fmaxf(h[e] + bb1, 0.f));
                    int bo = (row * 2048 + (goff + r16) * 2) ^ ((row & 7) << 4);
                    *(ushort*)(h1b + bo) = hv;
                }
                if (d < 16) {                              // 17th unit
                    bf16x8 wf01 = *(const bf16x8*)(w1p + 512);
                    bf16x8 wf11 = *(const bf16x8*)(w1p + 1536);
                    f32x4 g = {0,0,0,0};
                    g = MFMA(xa0, wf01, g, 0, 0, 0);
                    g = MFMA(xa1, wf11, g, 0, 0, 0);
                    if (r16 == 0) {
                        float bb2 = b1s[goff + 16];
                        #pragma unroll
                        for (int e = 0; e < 4; ++e) {
                            int row = q * 4 + e;
                            ushort hv = f2bf(fmaxf(g[e] + bb2, 0.f));
                            int bo = (row * 2048 + (goff + 16) * 2) ^ ((row & 7) << 4);
                            *(ushort*)(h1b + bo) = hv;
                        }
                    }
                }
            }

            // ---- phase b (MFMA, static classes; zero h1-tail makes over-read chunks free) ----
            f32x4 o1, o2 = {0,0,0,0};
            const ushort* w2p = W2f + w2off;
            const ushort* w2gp = W2g + (size_t)d * 9 * 512;
            if (t <= 17) {
                if (d < 16) phase_b<9, true>(w2p, w2gp, h1b, r16, q, lane8, o1, o2);
                else        phase_b<9, false>(w2p, w2gp, h1b, r16, q, lane8, o1, o2);
            }
            else if (t <= 25) phase_b<13, false>(w2p, w2gp, h1b, r16, q, lane8, o1, o2);
            else if (t <= 33) phase_b<17, false>(w2p, w2gp, h1b, r16, q, lane8, o1, o2);
            else if (t <= 42) phase_b<22, false>(w2p, w2gp, h1b, r16, q, lane8, o1, o2);
            else if (t <= 52) phase_b<27, false>(w2p, w2gp, h1b, r16, q, lane8, o1, o2);
            else              phase_b<32, false>(w2p, w2gp, h1b, r16, q, lane8, o1, o2);
            w2off += (size_t)nc_of(t) * 512;

            // ---- stage h2 group (C-layout -> A-layout via same-wave LDS round-trip) ----
            {
                float bb2 = b2s[goff + r16];
                #pragma unroll
                for (int e = 0; e < 4; ++e) {
                    int row = q * 4 + e;
                    ushort hv = f2bf(fmaxf(o1[e] + bb2, 0.f));
                    int bo = (row * 64 + r16 * 2) ^ (e << 4);
                    *(ushort*)((char*)h2s + bo) = hv;
                }
                if (r16 == 0) {                            // k=16 slot: value or zero
                    float bb3 = (d < 16) ? b2s[goff + 16] : 0.f;
                    #pragma unroll
                    for (int e = 0; e < 4; ++e) {
                        int row = q * 4 + e;
                        ushort hv = (d < 16) ? f2bf(fmaxf(o2[e] + bb3, 0.f)) : (ushort)0;
                        int bo = (row * 64 + 32) ^ (e << 4);
                        *(ushort*)((char*)h2s + bo) = hv;
                    }
                }
            }

            // ---- phase c (MFMA): acc += h2grp x W3grp ----
            {
                int abo = (r16 * 64 + q * 16) ^ ((r16 & 3) << 4);
                bf16x8 ha = *(const bf16x8*)((char*)h2s + abo);
                const ushort* w3p = W3f + (size_t)d * 4096 + lane8;
                bf16x8 f0 = *(const bf16x8*)(w3p);
                bf16x8 f1 = *(const bf16x8*)(w3p + 512);
                bf16x8 f2 = *(const bf16x8*)(w3p + 1024);
                bf16x8 f3 = *(const bf16x8*)(w3p + 1536);
                bf16x8 f4 = *(const bf16x8*)(w3p + 2048);
                bf16x8 f5 = *(const bf16x8*)(w3p + 2560);
                bf16x8 f6 = *(const bf16x8*)(w3p + 3072);
                bf16x8 f7 = *(const bf16x8*)(w3p + 3584);
                am0 = MFMA(ha, f0, am0, 0, 0, 0);
                am1 = MFMA(ha, f1, am1, 0, 0, 0);
                am2 = MFMA(ha, f2, am2, 0, 0, 0);
                am3 = MFMA(ha, f3, am3, 0, 0, 0);
                al0 = MFMA(ha, f4, al0, 0, 0, 0);
                al1 = MFMA(ha, f5, al1, 0, 0, 0);
                al2 = MFMA(ha, f6, al2, 0, 0, 0);
                al3 = MFMA(ha, f7, al3, 0, 0, 0);
            }
        }

        // ---- phase d: col t is final; owner lanes form x_t ----
        {
            f32x4 vm = (tt == 0) ? am0 : (tt == 1) ? am1 : (tt == 2) ? am2 : am3;
            f32x4 vl = (tt == 0) ? al0 : (tt == 1) ? al1 : (tt == 2) ? al2 : al3;
            if (r16 == oc) {
                #pragma unroll
                for (int e = 0; e < 4; ++e) {
                    int row = q * 4 + e;
                    float mu = vm[e] + b3mu;
                    float ls = vl[e] + b3ls;
                    float xv = uu[e] * expf(ls) + mu;
                    out[(size_t)(grow0 + row) * 64 + t] = xv;
                    xbs[row * 72 + t] = f2bf(xv);
                    lgd[row] += ls;
                }
            }
        }
    }

    if (lane < 16) out[(size_t)32768 * 64 + grow0 + lane] = lgd[lane];
}

extern "C" void kernel_launch(void* const* d_in, const int* in_sizes, int n_in,
                              void* d_out, int out_size, void* d_ws, size_t ws_size,
                              hipStream_t stream) {
    const float* U  = (const float*)d_in[0];
    const float* W1 = (const float*)d_in[1];
    const float* b1 = (const float*)d_in[2];
    const float* W2 = (const float*)d_in[3];
    const float* b2 = (const float*)d_in[4];
    const float* W3 = (const float*)d_in[5];
    const float* b3 = (const float*)d_in[6];
    float* out = (float*)d_out;

    char* ws = (char*)d_ws;
    ushort* W2f = (ushort*)ws;                        // 1,080,320 B (1055 chunks x 1KB)
    ushort* W2g = (ushort*)(ws + 1080320);            //   147,456 B
    ushort* W1f = (ushort*)(ws + 1227776);            //   258,048 B
    ushort* W3f = (ushort*)(ws + 1485824);            //   516,096 B
    float*  b1s = (float*)(ws + 2001920);             //     4,096 B
    float*  b2s = (float*)(ws + 2006016);             //     4,096 B  (total 2,010,112)

    prep_all<<<4032, 256, 0, stream>>>(W1, W2, W3, b1, b2, W2f, W2g, W1f, W3f, b1s, b2s);

    const int smem_bytes = 144640;   // 4 x (32768 h1 + 2304 xb + 1024 h2 + 64 logd)
    hipFuncSetAttribute(reinterpret_cast<const void*>(&maf_main),
                        hipFuncAttributeMaxDynamicSharedMemorySize, smem_bytes);
    maf_main<<<512, 256, smem_bytes, stream>>>(U, b3, W2f, W2g, W1f, W3f, b1s, b2s, out);
}

// Round 5
// 281.739 us; speedup vs baseline: 9.6609x; 1.2461x over previous
//
#include <hip/hip_runtime.h>
#include <hip/hip_bf16.h>
#include <stdint.h>

typedef __attribute__((ext_vector_type(8))) short bf16x8;
typedef __attribute__((ext_vector_type(4))) float f32x4;
typedef __attribute__((ext_vector_type(4))) unsigned int u32x4;

#define MFMA __builtin_amdgcn_mfma_f32_16x16x32_bf16

__device__ __forceinline__ ushort f2bf(float v) {
    __hip_bfloat16 b = __float2bfloat16(v);
    return *reinterpret_cast<ushort*>(&b);
}

// Unit mapping: group g (=degree), main m-th unit: h = g + 63*m (m=0..15);
// extra unit of group g<16: h = 1008+g.
// Register chunk layout: chunk j (0..31) = main units of groups 2j (k 0..15), 2j+1 (k 16..31);
// chunk 32 = extras (k = g for g<16, rest zero).
//
// W2f2 [63 d][33 kc][512] bf16 B-frags: col=lane&15 -> out unit d+63*col; k-slot s=(lane>>4)*8+e
//      -> in unit per chunk mapping (zero-padded).
// W2g2 [16 d][9 j][512]  B-frags for out unit 1008+d (col 0 only); j<8 -> chunk j, j=8 -> chunk 32.
// W1f  [63 d][2 kc2][2 nt][512] phase-a B-frags: k = input dim kc2*32+..., col -> unit d+63*col
//      (nt=1: col 0 -> 1008+d).
// W3f  [63 d][8 cb][512] phase-c B-frags: col -> out col cb*16+col; k-slot s -> h2 unit d+63*s
//      (s=16 -> 1008+d when d<16; else zero).
__global__ void prep_all(const float* __restrict__ W1, const float* __restrict__ W2,
                         const float* __restrict__ W3, const float* __restrict__ b1,
                         const float* __restrict__ b2,
                         ushort* __restrict__ W2f2, ushort* __restrict__ W2g2,
                         ushort* __restrict__ W1f, ushort* __restrict__ W3f,
                         float* __restrict__ b1s2, float* __restrict__ b1e,
                         float* __restrict__ b2s2, float* __restrict__ b2e)
{
    int idx = blockIdx.x * 256 + threadIdx.x;
    if (idx < 63 * 33 * 512) {
        int d = idx / (33 * 512); int rem = idx - d * 33 * 512;
        int kc = rem >> 9, r = rem & 511;
        int lane = r >> 3, e = r & 7;
        int col = lane & 15, s = ((lane >> 4) << 3) + e;
        int hout = d + 63 * col;
        float v = 0.f;
        if (kc < 32) {
            int g = 2 * kc + (s >> 4), m = s & 15;
            if (g <= 62) v = W2[(size_t)(g + 63 * m) * 1024 + hout];
        } else if (s < 16) {
            v = W2[(size_t)(1008 + s) * 1024 + hout];
        }
        W2f2[idx] = f2bf(v);
    }
    if (idx < 16 * 9 * 512) {
        int d = idx / (9 * 512); int rem = idx - d * 9 * 512;
        int j = rem >> 9, r = rem & 511;
        int lane = r >> 3, e = r & 7;
        int col = lane & 15, s = ((lane >> 4) << 3) + e;
        float v = 0.f;
        if (col == 0) {
            int hout = 1008 + d;
            if (j < 8) {
                int g = 2 * j + (s >> 4), m = s & 15;
                if (g <= 62) v = W2[(size_t)(g + 63 * m) * 1024 + hout];
            } else if (s < 16) {
                v = W2[(size_t)(1008 + s) * 1024 + hout];
            }
        }
        W2g2[idx] = f2bf(v);
    }
    if (idx < 63 * 2048) {
        int d = idx >> 11; int rem = idx & 2047;
        int kc2 = rem >> 10, nt = (rem >> 9) & 1, r = rem & 511;
        int lane = r >> 3, e = r & 7;
        int col = lane & 15, k = kc2 * 32 + ((lane >> 4) << 3) + e;
        float v = 0.f;
        if (nt == 0) v = W1[(size_t)k * 1024 + d + 63 * col];
        else if (d < 16 && col == 0) v = W1[(size_t)k * 1024 + 1008 + d];
        W1f[idx] = f2bf(v);
    }
    if (idx < 63 * 8 * 512) {
        int d = idx >> 12; int rem = idx & 4095;
        int cb = rem >> 9, r = rem & 511;
        int lane = r >> 3, e = r & 7;
        int ncol = lane & 15, s = ((lane >> 4) << 3) + e;
        int c = cb * 16 + ncol;
        float v = 0.f;
        if (s < 16) v = W3[(size_t)(d + 63 * s) * 128 + c];
        else if (s == 16 && d < 16) v = W3[(size_t)(1008 + d) * 128 + c];
        W3f[idx] = f2bf(v);
    }
    if (idx < 1008) {
        int d = idx >> 4, m = idx & 15;
        b1s2[idx] = b1[d + 63 * m];
        b2s2[idx] = b2[d + 63 * m];
    }
    if (idx < 16) { b1e[idx] = b1[1008 + idx]; b2e[idx] = b2[1008 + idx]; }
}

// phase b: h2 group = sum over chunks of h1f[kc] x W2 B-frag; chunk list = 0..CM-1, then 32.
template<int CM, bool T2>
__device__ __forceinline__ void phase_b(const char* __restrict__ w2p,
                                        const char* __restrict__ w2gp,
                                        const bf16x8 (&h1f)[33], int lane16,
                                        f32x4& o1, f32x4& o2)
{
    constexpr int N = CM + 1;
    constexpr int PF = (N < 4) ? N : 4;
    bf16x8 bb[4]; bf16x8 gg[4];
    #pragma unroll
    for (int i = 0; i < PF; ++i) {
        int kc = (i < CM) ? i : 32;
        bb[i] = *(const bf16x8*)(w2p + kc * 1024 + lane16);
        if constexpr (T2) gg[i] = *(const bf16x8*)(w2gp + i * 1024 + lane16);
    }
    f32x4 c0 = {0,0,0,0}, c1 = {0,0,0,0}, c2 = {0,0,0,0}, c3 = {0,0,0,0};
    f32x4 g0 = {0,0,0,0}, g1 = {0,0,0,0};
    #pragma unroll
    for (int i = 0; i < N; ++i) {
        int kc = (i < CM) ? i : 32;
        bf16x8 a = h1f[kc];
        bf16x8 b = bb[i & 3];
        if ((i & 3) == 0)      c0 = MFMA(a, b, c0, 0, 0, 0);
        else if ((i & 3) == 1) c1 = MFMA(a, b, c1, 0, 0, 0);
        else if ((i & 3) == 2) c2 = MFMA(a, b, c2, 0, 0, 0);
        else                   c3 = MFMA(a, b, c3, 0, 0, 0);
        if constexpr (T2) {
            bf16x8 g = gg[i & 3];
            if (i & 1) g1 = MFMA(a, g, g1, 0, 0, 0);
            else       g0 = MFMA(a, g, g0, 0, 0, 0);
        }
        if (i + 4 < N) {
            int kn = (i + 4 < CM) ? (i + 4) : 32;
            bb[i & 3] = *(const bf16x8*)(w2p + kn * 1024 + lane16);
            if constexpr (T2) gg[i & 3] = *(const bf16x8*)(w2gp + (i + 4) * 1024 + lane16);
        }
    }
    o1 = (c0 + c1) + (c2 + c3);
    if constexpr (T2) o2 = g0 + g1;
}

// 4 waves/WG, each wave owns a private 16-row batch slice; h1 history in registers.
__global__ __launch_bounds__(256, 2)
void maf_main(const float* __restrict__ U, const float* __restrict__ b3,
              const ushort* __restrict__ W2f2, const ushort* __restrict__ W2g2,
              const ushort* __restrict__ W1f, const ushort* __restrict__ W3f,
              const float* __restrict__ b1s2, const float* __restrict__ b1e,
              const float* __restrict__ b2s2, const float* __restrict__ b2e,
              float* __restrict__ out)
{
    __shared__ char smem[4*1024 + 4*1024 + 4*1024 + 4*2304 + 4*64];  // 21.8 KB/WG
    const int tid = threadIdx.x;
    const int w = tid >> 6, lane = tid & 63;
    const int r16 = lane & 15, q = lane >> 4;
    const int lane16 = lane << 4;
    char*   stgm = smem + w * 1024;                      // chunk-pair transpose staging
    char*   stge = smem + 4096 + w * 1024;               // extras staging (accumulating)
    char*   h2s  = smem + 8192 + w * 1024;               // h2 group staging
    ushort* xbs  = (ushort*)(smem + 12288 + w * 2304);   // [16][72] bf16 x mirror
    float*  lgd  = (float*)(smem + 21504 + w * 64);      // [16] logdet
    const int grow0 = blockIdx.x * 64 + w * 16;

    {
        u32x4 z = {0u, 0u, 0u, 0u};
        for (int i = lane; i < 64; i += 64) *(u32x4*)(stge + i * 16) = z;       // 1KB
        for (int i = lane; i < 64; i += 64) *(u32x4*)(h2s + i * 16) = z;        // 1KB
        for (int i = lane; i < 576; i += 64) ((uint32_t*)xbs)[i] = 0u;          // 2304B
        if (lane < 16) lgd[lane] = 0.f;
    }

    bf16x8 h1f[33];
    #pragma unroll
    for (int i = 0; i < 33; ++i) h1f[i] = (bf16x8){0,0,0,0,0,0,0,0};

    // output acc: am = mu cols tile n -> cols n*16.., al = ls cols 64+n*16..
    f32x4 am0={0,0,0,0},am1={0,0,0,0},am2={0,0,0,0},am3={0,0,0,0};
    f32x4 al0={0,0,0,0},al1={0,0,0,0},al2={0,0,0,0},al3={0,0,0,0};

    for (int t = 0; t < 64; ++t) {
        const int tt = t >> 4, oc = t & 15;
        const float b3mu = b3[t], b3ls = b3[64 + t];
        float uu[4] = {0.f, 0.f, 0.f, 0.f};
        if (r16 == oc) {
            #pragma unroll
            for (int e = 0; e < 4; ++e)
                uu[e] = U[(size_t)(grow0 + q * 4 + e) * 64 + t];
        }

        if (t > 0) {
            const int d = t - 1;
            const int jc = d >> 1;

            // ---- phase a (MFMA): h1 group d ----
            {
                const char* w1p = (const char*)W1f + (size_t)d * 4096 + lane16;
                bf16x8 wf00 = *(const bf16x8*)(w1p);
                bf16x8 wf10 = *(const bf16x8*)(w1p + 2048);
                bf16x8 xa0 = *(const bf16x8*)(xbs + r16 * 72 + q * 8);
                bf16x8 xa1 = *(const bf16x8*)(xbs + r16 * 72 + 32 + q * 8);
                f32x4 h = {0,0,0,0};
                h = MFMA(xa0, wf00, h, 0, 0, 0);
                h = MFMA(xa1, wf10, h, 0, 0, 0);
                float bb1 = b1s2[d * 16 + r16];
                #pragma unroll
                for (int e = 0; e < 4; ++e) {
                    int row = q * 4 + e;
                    ushort hv = f2bf(fmaxf(h[e] + bb1, 0.f));
                    *(ushort*)(stgm + ((row * 64 + ((d & 1) << 5) + r16 * 2) ^ ((row & 3) << 4))) = hv;
                    if (!(d & 1))
                        *(ushort*)(stgm + ((row * 64 + 32 + r16 * 2) ^ ((row & 3) << 4))) = 0;
                }
                if (d < 16) {                              // 17th (extra) unit
                    bf16x8 wf01 = *(const bf16x8*)(w1p + 1024);
                    bf16x8 wf11 = *(const bf16x8*)(w1p + 3072);
                    f32x4 g = {0,0,0,0};
                    g = MFMA(xa0, wf01, g, 0, 0, 0);
                    g = MFMA(xa1, wf11, g, 0, 0, 0);
                    if (r16 == 0) {
                        float be = b1e[d];
                        #pragma unroll
                        for (int e = 0; e < 4; ++e) {
                            int row = q * 4 + e;
                            ushort hv = f2bf(fmaxf(g[e] + be, 0.f));
                            *(ushort*)(stge + ((row * 64 + d * 2) ^ ((row & 3) << 4))) = hv;
                        }
                    }
                }
            }
            // read back updated chunk frag(s) into registers
            {
                bf16x8 nf = *(const bf16x8*)(stgm + ((r16 * 64 + q * 16) ^ ((r16 & 3) << 4)));
                switch (jc) {
                    case 0:  h1f[0]=nf;  break; case 1:  h1f[1]=nf;  break;
                    case 2:  h1f[2]=nf;  break; case 3:  h1f[3]=nf;  break;
                    case 4:  h1f[4]=nf;  break; case 5:  h1f[5]=nf;  break;
                    case 6:  h1f[6]=nf;  break; case 7:  h1f[7]=nf;  break;
                    case 8:  h1f[8]=nf;  break; case 9:  h1f[9]=nf;  break;
                    case 10: h1f[10]=nf; break; case 11: h1f[11]=nf; break;
                    case 12: h1f[12]=nf; break; case 13: h1f[13]=nf; break;
                    case 14: h1f[14]=nf; break; case 15: h1f[15]=nf; break;
                    case 16: h1f[16]=nf; break; case 17: h1f[17]=nf; break;
                    case 18: h1f[18]=nf; break; case 19: h1f[19]=nf; break;
                    case 20: h1f[20]=nf; break; case 21: h1f[21]=nf; break;
                    case 22: h1f[22]=nf; break; case 23: h1f[23]=nf; break;
                    case 24: h1f[24]=nf; break; case 25: h1f[25]=nf; break;
                    case 26: h1f[26]=nf; break; case 27: h1f[27]=nf; break;
                    case 28: h1f[28]=nf; break; case 29: h1f[29]=nf; break;
                    case 30: h1f[30]=nf; break; default: h1f[31]=nf; break;
                }
                if (d < 16)
                    h1f[32] = *(const bf16x8*)(stge + ((r16 * 64 + q * 16) ^ ((r16 & 3) << 4)));
            }

            // ---- phase b (MFMA, register A-frags, streamed B-frags) ----
            f32x4 o1, o2 = {0,0,0,0};
            const char* w2p = (const char*)W2f2 + (size_t)d * 33 * 1024;
            const char* w2gp = (const char*)W2g2 + (size_t)d * 9 * 1024;
            if (t <= 16)      phase_b<8,  true >(w2p, w2gp, h1f, lane16, o1, o2);
            else if (t <= 28) phase_b<14, false>(w2p, w2gp, h1f, lane16, o1, o2);
            else if (t <= 40) phase_b<20, false>(w2p, w2gp, h1f, lane16, o1, o2);
            else if (t <= 52) phase_b<26, false>(w2p, w2gp, h1f, lane16, o1, o2);
            else              phase_b<32, false>(w2p, w2gp, h1f, lane16, o1, o2);

            // ---- phase c: W3 loads early, h2 transpose staging, 8 MFMAs ----
            {
                const char* w3p = (const char*)W3f + (size_t)d * 8192 + lane16;
                bf16x8 f0 = *(const bf16x8*)(w3p);
                bf16x8 f1 = *(const bf16x8*)(w3p + 1024);
                bf16x8 f2 = *(const bf16x8*)(w3p + 2048);
                bf16x8 f3 = *(const bf16x8*)(w3p + 3072);
                bf16x8 f4 = *(const bf16x8*)(w3p + 4096);
                bf16x8 f5 = *(const bf16x8*)(w3p + 5120);
                bf16x8 f6 = *(const bf16x8*)(w3p + 6144);
                bf16x8 f7 = *(const bf16x8*)(w3p + 7168);
                float bb2 = b2s2[d * 16 + r16];
                #pragma unroll
                for (int e = 0; e < 4; ++e) {
                    int row = q * 4 + e;
                    ushort hv = f2bf(fmaxf(o1[e] + bb2, 0.f));
                    *(ushort*)(h2s + ((row * 64 + r16 * 2) ^ ((row & 3) << 4))) = hv;
                }
                if (r16 == 0) {
                    float be2 = (d < 16) ? b2e[d] : 0.f;
                    #pragma unroll
                    for (int e = 0; e < 4; ++e) {
                        int row = q * 4 + e;
                        ushort hv = (d < 16) ? f2bf(fmaxf(o2[e] + be2, 0.f)) : (ushort)0;
                        *(ushort*)(h2s + ((row * 64 + 32) ^ ((row & 3) << 4))) = hv;
                    }
                }
                bf16x8 ha = *(const bf16x8*)(h2s + ((r16 * 64 + q * 16) ^ ((r16 & 3) << 4)));
                am0 = MFMA(ha, f0, am0, 0, 0, 0);
                am1 = MFMA(ha, f1, am1, 0, 0, 0);
                am2 = MFMA(ha, f2, am2, 0, 0, 0);
                am3 = MFMA(ha, f3, am3, 0, 0, 0);
                al0 = MFMA(ha, f4, al0, 0, 0, 0);
                al1 = MFMA(ha, f5, al1, 0, 0, 0);
                al2 = MFMA(ha, f6, al2, 0, 0, 0);
                al3 = MFMA(ha, f7, al3, 0, 0, 0);
            }
        }

        // ---- phase d: col t final; owner lanes form x_t ----
        {
            f32x4 vm = (tt == 0) ? am0 : (tt == 1) ? am1 : (tt == 2) ? am2 : am3;
            f32x4 vl = (tt == 0) ? al0 : (tt == 1) ? al1 : (tt == 2) ? al2 : al3;
            if (r16 == oc) {
                #pragma unroll
                for (int e = 0; e < 4; ++e) {
                    int row = q * 4 + e;
                    float mu = vm[e] + b3mu;
                    float ls = vl[e] + b3ls;
                    float xv = uu[e] * expf(ls) + mu;
                    out[(size_t)(grow0 + row) * 64 + t] = xv;
                    xbs[row * 72 + t] = f2bf(xv);
                    lgd[row] += ls;
                }
            }
        }
    }

    if (lane < 16) out[(size_t)32768 * 64 + grow0 + lane] = lgd[lane];
}

extern "C" void kernel_launch(void* const* d_in, const int* in_sizes, int n_in,
                              void* d_out, int out_size, void* d_ws, size_t ws_size,
                              hipStream_t stream) {
    const float* U  = (const float*)d_in[0];
    const float* W1 = (const float*)d_in[1];
    const float* b1 = (const float*)d_in[2];
    const float* W2 = (const float*)d_in[3];
    const float* b2 = (const float*)d_in[4];
    const float* W3 = (const float*)d_in[5];
    const float* b3 = (const float*)d_in[6];
    float* out = (float*)d_out;

    char* ws = (char*)d_ws;
    ushort* W2f2 = (ushort*)ws;                      // 2,128,896 B
    ushort* W2g2 = (ushort*)(ws + 2128896);          //   147,456 B
    ushort* W1f  = (ushort*)(ws + 2276352);          //   258,048 B
    ushort* W3f  = (ushort*)(ws + 2534400);          //   516,096 B
    float*  b1s2 = (float*)(ws + 3050496);           //     4,096 B (1008 used)
    float*  b1e  = (float*)(ws + 3054592);           //       128 B
    float*  b2s2 = (float*)(ws + 3054720);           //     4,032 B
    float*  b2e  = (float*)(ws + 3058752);           //        64 B

    prep_all<<<4160, 256, 0, stream>>>(W1, W2, W3, b1, b2,
                                       W2f2, W2g2, W1f, W3f, b1s2, b1e, b2s2, b2e);
    maf_main<<<512, 256, 0, stream>>>(U, b3, W2f2, W2g2, W1f, W3f,
                                      b1s2, b1e, b2s2, b2e, out);
}